// Round 1
// baseline (895.511 us; speedup 1.0000x reference)
//
#include <hip/hip_runtime.h>
#include <hip/hip_bf16.h>

typedef __attribute__((ext_vector_type(4))) float f32x4;
typedef __attribute__((ext_vector_type(8))) short s16x8;
typedef __attribute__((ext_vector_type(4))) short s16x4;

#define MFMA16(A, B, C) __builtin_amdgcn_mfma_f32_16x16x32_bf16((A), (B), (C), 0, 0, 0)

__device__ __forceinline__ ushort f2bf(float f) {
    __hip_bfloat16 h = __float2bfloat16(f);
    return *reinterpret_cast<ushort*>(&h);
}

// ---------------- convert fp32 -> bf16 (vectorized x4) ----------------
__global__ void k_cvt(const float* __restrict__ in, ushort* __restrict__ out, int n) {
    int i = (blockIdx.x * 256 + threadIdx.x) * 4;
    if (i + 3 >= n) return;
    float4 v = *(const float4*)(in + i);
    ushort4 o;
    o.x = f2bf(v.x); o.y = f2bf(v.y); o.z = f2bf(v.z); o.w = f2bf(v.w);
    *(ushort4*)(out + i) = o;
}

// ---------------- transpose weight [K,N] f32 -> [N,K] bf16 ----------------
__global__ void k_twT(const float* __restrict__ w, ushort* __restrict__ wt, int K, int N) {
    __shared__ float tile[32][33];
    int k0 = blockIdx.x * 32, n0 = blockIdx.y * 32;
    int tx = threadIdx.x & 31, ty = threadIdx.x >> 5;   // 32 x 8
    #pragma unroll
    for (int i = ty; i < 32; i += 8)
        tile[i][tx] = w[(size_t)(k0 + i) * N + n0 + tx];
    __syncthreads();
    #pragma unroll
    for (int i = ty; i < 32; i += 8)
        wt[(size_t)(n0 + i) * K + k0 + tx] = f2bf(tile[tx][i]);
}

// ---------------- zero the key-pad region of Vt (keys 300..319) ----------------
__global__ void k_padVt(ushort* __restrict__ Vt) {
    int i = blockIdx.x * 256 + threadIdx.x;   // < 131072*20
    int row = i / 20, k = 300 + i % 20;
    Vt[(size_t)row * 320 + k] = 0;
}

// ---------------- GEMM: A[M,K]bf16 @ BT[N,K]bf16^T + bias ----------------
// OUT=0: store bf16 [M,N].  OUT=1: store bf16 transposed into Vt layout.
// OUT=2: store f32 [M,N] with +bias +resid.
template <int OUT>
__global__ __launch_bounds__(256) void k_gemm(const ushort* __restrict__ A,
                                              const ushort* __restrict__ BT,
                                              const float* __restrict__ bias,
                                              const float* __restrict__ resid,
                                              void* __restrict__ outp,
                                              int M, int N, int K) {
    __shared__ ushort As[128][40];   // pad 32 -> 40 to break bank conflicts
    __shared__ ushort Bs[128][40];
    int m0 = blockIdx.x * 128, n0 = blockIdx.y * 128;
    int t = threadIdx.x, l = t & 63, wid = t >> 6;
    int wm = (wid >> 1) * 64, wn = (wid & 1) * 64;
    int lr = l & 15, lg = l >> 4;

    f32x4 acc[4][4];
    #pragma unroll
    for (int i = 0; i < 4; ++i)
        #pragma unroll
        for (int j = 0; j < 4; ++j)
            acc[i][j] = (f32x4){0.f, 0.f, 0.f, 0.f};

    for (int k0 = 0; k0 < K; k0 += 32) {
        #pragma unroll
        for (int c = 0; c < 2; ++c) {
            int cid = t + 256 * c;              // 0..511
            int row = cid >> 2, col = (cid & 3) * 8;
            s16x8 va = *(const s16x8*)(A + (size_t)(m0 + row) * K + k0 + col);
            *(s16x8*)(&As[row][col]) = va;
            s16x8 vb = *(const s16x8*)(BT + (size_t)(n0 + row) * K + k0 + col);
            *(s16x8*)(&Bs[row][col]) = vb;
        }
        __syncthreads();
        s16x8 af[4], bfr[4];
        #pragma unroll
        for (int i = 0; i < 4; ++i) af[i] = *(const s16x8*)(&As[wm + i * 16 + lr][lg * 8]);
        #pragma unroll
        for (int j = 0; j < 4; ++j) bfr[j] = *(const s16x8*)(&Bs[wn + j * 16 + lr][lg * 8]);
        #pragma unroll
        for (int i = 0; i < 4; ++i)
            #pragma unroll
            for (int j = 0; j < 4; ++j)
                acc[i][j] = MFMA16(af[i], bfr[j], acc[i][j]);
        __syncthreads();
    }

    if (OUT == 0) {
        ushort* out = (ushort*)outp;
        #pragma unroll
        for (int i = 0; i < 4; ++i)
            #pragma unroll
            for (int j = 0; j < 4; ++j) {
                int col = n0 + wn + j * 16 + lr;
                float bv = bias[col];
                #pragma unroll
                for (int r = 0; r < 4; ++r) {
                    int row = m0 + wm + i * 16 + lg * 4 + r;
                    out[(size_t)row * N + col] = f2bf(acc[i][j][r] + bv);
                }
            }
    } else if (OUT == 1) {
        ushort* Vt = (ushort*)outp;
        #pragma unroll
        for (int i = 0; i < 4; ++i)
            #pragma unroll
            for (int j = 0; j < 4; ++j) {
                int col = n0 + wn + j * 16 + lr;
                float bv = bias[col];
                int hh = col >> 8, v = col & 255;
                #pragma unroll
                for (int r = 0; r < 4; ++r) {
                    int row = m0 + wm + i * 16 + lg * 4 + r;
                    int bb = row / 300, key = row - bb * 300;
                    Vt[(((size_t)bb * 8 + hh) * 256 + v) * 320 + key] = f2bf(acc[i][j][r] + bv);
                }
            }
    } else {
        float* out = (float*)outp;
        #pragma unroll
        for (int i = 0; i < 4; ++i)
            #pragma unroll
            for (int j = 0; j < 4; ++j) {
                int col = n0 + wn + j * 16 + lr;
                float bv = bias[col];
                #pragma unroll
                for (int r = 0; r < 4; ++r) {
                    int row = m0 + wm + i * 16 + lg * 4 + r;
                    size_t idx = (size_t)row * N + col;
                    out[idx] = acc[i][j][r] + bv + resid[idx];
                }
            }
    }
}

// ---------------- fused attention per (q-tile, h, b) ----------------
// scores = (Q @ G^T) * wb + bias; gelu exact; softmax over keys; O = P @ V
__global__ __launch_bounds__(256) void k_attn(const ushort* __restrict__ qf_bf,
                                              const ushort* __restrict__ G_bf,
                                              const ushort* __restrict__ Vt,
                                              const float* __restrict__ wb,
                                              const float* __restrict__ bias,
                                              ushort* __restrict__ O) {
    __shared__ ushort P[64][328];   // 64 q-rows x 320 keys (pad to 328)
    int qt = blockIdx.x, h = blockIdx.y, b = blockIdx.z;
    int t = threadIdx.x, l = t & 63, w = t >> 6;
    int lr = l & 15, lg = l >> 4;

    // Q fragments (A operand), rows = lane&15
    int qrow = qt * 64 + w * 16 + lr;
    int qr = min(qrow, 299);
    const ushort* qp = qf_bf + ((size_t)(b * 300 + qr)) * 512 + h * 64 + lg * 8;
    s16x8 aq0 = *(const s16x8*)(qp);
    s16x8 aq1 = *(const s16x8*)(qp + 32);

    // ---- scores + gelu, kept in registers ----
    float sc[19][4];
    #pragma unroll
    for (int kt = 0; kt < 19; ++kt) {
        int key = kt * 16 + lr;
        int kc = min(key, 299);
        const ushort* gp = G_bf + (size_t)(b * 300 + kc) * 512 + h * 64 + lg * 8;
        s16x8 bg0 = *(const s16x8*)(gp);
        s16x8 bg1 = *(const s16x8*)(gp + 32);
        f32x4 a = (f32x4){0.f, 0.f, 0.f, 0.f};
        a = MFMA16(aq0, bg0, a);
        a = MFMA16(aq1, bg1, a);
        int kcol = kt * 16 + lr;        // key of this lane in C layout
        int kcl = min(kcol, 299);
        #pragma unroll
        for (int r = 0; r < 4; ++r) {
            int q = qt * 64 + w * 16 + lg * 4 + r;
            int ql = min(q, 299);
            size_t bidx = ((size_t)h * 300 + ql) * 300 + kcl;
            float x = a[r] * wb[bidx] + bias[bidx];
            float g = 0.5f * x * (1.0f + erff(x * 0.70710678118f));
            sc[kt][r] = (kcol < 300) ? g : -3.0e38f;
        }
    }

    // ---- softmax over keys (reduce across 16 lanes within lg-group) ----
    float invs[4];
    #pragma unroll
    for (int r = 0; r < 4; ++r) {
        float m = -3.0e38f;
        #pragma unroll
        for (int kt = 0; kt < 19; ++kt) m = fmaxf(m, sc[kt][r]);
        #pragma unroll
        for (int o = 1; o < 16; o <<= 1) m = fmaxf(m, __shfl_xor(m, o));
        float s = 0.f;
        #pragma unroll
        for (int kt = 0; kt < 19; ++kt) {
            float p = __expf(sc[kt][r] - m);
            sc[kt][r] = p;
            s += p;
        }
        #pragma unroll
        for (int o = 1; o < 16; o <<= 1) s += __shfl_xor(s, o);
        invs[r] = 1.0f / s;
    }
    #pragma unroll
    for (int kt = 0; kt < 19; ++kt)
        #pragma unroll
        for (int r = 0; r < 4; ++r)
            P[w * 16 + lg * 4 + r][kt * 16 + lr] = f2bf(sc[kt][r] * invs[r]);
    // zero pad keys 304..319
    {
        int q = t & 63, k0 = 304 + (t >> 6) * 4;
        *(s16x4*)(&P[q][k0]) = (s16x4){0, 0, 0, 0};
    }
    __syncthreads();

    // ---- PV: O[16q x 256v] per wave, K = 320 keys in 10 chunks ----
    s16x8 pa[10];
    #pragma unroll
    for (int kc = 0; kc < 10; ++kc)
        pa[kc] = *(const s16x8*)(&P[w * 16 + lr][kc * 32 + lg * 8]);

    const ushort* vbase = Vt + ((size_t)(b * 8 + h) * 256) * 320 + lg * 8;
    #pragma unroll
    for (int nt = 0; nt < 16; ++nt) {
        f32x4 a = (f32x4){0.f, 0.f, 0.f, 0.f};
        const ushort* vp = vbase + (size_t)(nt * 16 + lr) * 320;
        #pragma unroll
        for (int kc = 0; kc < 10; ++kc) {
            s16x8 bv = *(const s16x8*)(vp + kc * 32);
            a = MFMA16(pa[kc], bv, a);
        }
        #pragma unroll
        for (int r = 0; r < 4; ++r) {
            int q = qt * 64 + w * 16 + lg * 4 + r;
            if (q < 300)
                O[((size_t)(b * 300 + q)) * 2048 + h * 256 + nt * 16 + lr] = f2bf(a[r]);
        }
    }
}

extern "C" void kernel_launch(void* const* d_in, const int* in_sizes, int n_in,
                              void* d_out, int out_size, void* d_ws, size_t ws_size,
                              hipStream_t stream) {
    const float* qf    = (const float*)d_in[0];
    const float* bias  = (const float*)d_in[1];
    const float* W_gen = (const float*)d_in[2];
    const float* b_gen = (const float*)d_in[3];
    const float* W_val = (const float*)d_in[4];
    const float* b_val = (const float*)d_in[5];
    const float* W_out = (const float*)d_in[6];
    const float* b_out = (const float*)d_in[7];
    const float* wb    = (const float*)d_in[8];
    float* out = (float*)d_out;

    char* ws = (char*)d_ws;
    ushort* qf_bf = (ushort*)(ws);                       // 19,660,800 B
    ushort* G_bf  = (ushort*)(ws + 19660800);            // 19,660,800 B
    ushort* Vt    = (ushort*)(ws + 39321600);            // 83,886,080 B  (131072 x 320)
    ushort* O_bf  = (ushort*)(ws + 123207680);           // 78,643,200 B
    ushort* WgT   = (ushort*)(ws + 201850880);           //    524,288 B
    ushort* WvT   = (ushort*)(ws + 202375168);           //  2,097,152 B
    ushort* WoT   = (ushort*)(ws + 204472320);           //  2,097,152 B  -> total 206,569,472

    // stage 0: conversions / transposes / pad
    k_cvt<<<dim3(9600), dim3(256), 0, stream>>>(qf, qf_bf, 9830400);
    k_twT<<<dim3(16, 16), dim3(256), 0, stream>>>(W_gen, WgT, 512, 512);
    k_twT<<<dim3(16, 64), dim3(256), 0, stream>>>(W_val, WvT, 512, 2048);
    k_twT<<<dim3(64, 16), dim3(256), 0, stream>>>(W_out, WoT, 2048, 512);
    k_padVt<<<dim3(10240), dim3(256), 0, stream>>>(Vt);

    // stage 1: G = qf@W_gen + b_gen ; V^T = (qf@W_val + b_val) transposed
    k_gemm<0><<<dim3(150, 4),  dim3(256), 0, stream>>>(qf_bf, WgT, b_gen, nullptr, G_bf, 19200, 512, 512);
    k_gemm<1><<<dim3(150, 16), dim3(256), 0, stream>>>(qf_bf, WvT, b_val, nullptr, Vt,   19200, 2048, 512);

    // stage 2: fused attention
    k_attn<<<dim3(5, 8, 64), dim3(256), 0, stream>>>(qf_bf, G_bf, Vt, wb, bias, O_bf);

    // stage 3: out = O @ W_out + b_out + qf
    k_gemm<2><<<dim3(150, 4), dim3(256), 0, stream>>>(O_bf, WoT, b_out, qf, out, 19200, 512, 2048);
}

// Round 2
// 503.096 us; speedup vs baseline: 1.7800x; 1.7800x over previous
//
#include <hip/hip_runtime.h>
#include <hip/hip_bf16.h>

typedef __attribute__((ext_vector_type(4))) float f32x4;
typedef __attribute__((ext_vector_type(8))) short s16x8;
typedef __attribute__((ext_vector_type(4))) short s16x4;

#define MFMA16(A, B, C) __builtin_amdgcn_mfma_f32_16x16x32_bf16((A), (B), (C), 0, 0, 0)

__device__ __forceinline__ ushort f2bf(float f) {
    __hip_bfloat16 h = __float2bfloat16(f);
    return *reinterpret_cast<ushort*>(&h);
}

// branchless exact GELU via Abramowitz-Stegun 7.1.26 erf (|err| <= 1.5e-7)
__device__ __forceinline__ float gelu_exact(float x) {
    float z = 0.70710678118f * x;
    float az = fabsf(z);
    float t = 1.0f / fmaf(0.3275911f, az, 1.0f);
    float poly = t * (0.254829592f + t * (-0.284496736f + t * (1.421413741f +
                 t * (-1.453152027f + t * 1.061405429f))));
    float e = __expf(-az * az);
    float erfv = copysignf(1.0f - poly * e, z);
    return 0.5f * x * (1.0f + erfv);
}

// ---------------- convert fp32 -> bf16 (vectorized x4) ----------------
__global__ void k_cvt(const float* __restrict__ in, ushort* __restrict__ out, int n) {
    int i = (blockIdx.x * 256 + threadIdx.x) * 4;
    if (i + 3 >= n) return;
    float4 v = *(const float4*)(in + i);
    ushort4 o;
    o.x = f2bf(v.x); o.y = f2bf(v.y); o.z = f2bf(v.z); o.w = f2bf(v.w);
    *(ushort4*)(out + i) = o;
}

// ---------------- transpose weight [K,N] f32 -> [N,K] bf16 ----------------
__global__ void k_twT(const float* __restrict__ w, ushort* __restrict__ wt, int K, int N) {
    __shared__ float tile[32][33];
    int k0 = blockIdx.x * 32, n0 = blockIdx.y * 32;
    int tx = threadIdx.x & 31, ty = threadIdx.x >> 5;   // 32 x 8
    #pragma unroll
    for (int i = ty; i < 32; i += 8)
        tile[i][tx] = w[(size_t)(k0 + i) * N + n0 + tx];
    __syncthreads();
    #pragma unroll
    for (int i = ty; i < 32; i += 8)
        wt[(size_t)(n0 + i) * K + k0 + tx] = f2bf(tile[tx][i]);
}

// ---------------- zero key-pad (keys 300..319) in tiled Vt ----------------
// Vt tiled layout: [(b*8+h)][kc(10)][v(256)][k32(32)] ushort
__global__ void k_padVt(ushort* __restrict__ Vt) {
    int i = blockIdx.x * 256 + threadIdx.x;   // < 131072*20
    int row = i / 20;                // (b*8+h)*256 + v
    int k = 300 + (i - row * 20);    // 300..319
    int bh = row >> 8, v = row & 255;
    Vt[(((size_t)bh * 10 + 9) * 256 + v) * 32 + (k - 288)] = 0;
}

// ---------------- GEMM: A[M,K]bf16 @ BT[N,K]bf16^T + bias ----------------
// OUT=0: store bf16 [M,N].  OUT=1: store bf16 into tiled Vt layout.
// OUT=2: store f32 [M,N] with +bias +resid.
template <int OUT>
__global__ __launch_bounds__(256) void k_gemm(const ushort* __restrict__ A,
                                              const ushort* __restrict__ BT,
                                              const float* __restrict__ bias,
                                              const float* __restrict__ resid,
                                              void* __restrict__ outp,
                                              int M, int N, int K) {
    __shared__ ushort As[128][40];   // pad 32 -> 40 to break bank conflicts
    __shared__ ushort Bs[128][40];
    int m0 = blockIdx.x * 128, n0 = blockIdx.y * 128;
    int t = threadIdx.x, l = t & 63, wid = t >> 6;
    int wm = (wid >> 1) * 64, wn = (wid & 1) * 64;
    int lr = l & 15, lg = l >> 4;

    f32x4 acc[4][4];
    #pragma unroll
    for (int i = 0; i < 4; ++i)
        #pragma unroll
        for (int j = 0; j < 4; ++j)
            acc[i][j] = (f32x4){0.f, 0.f, 0.f, 0.f};

    for (int k0 = 0; k0 < K; k0 += 32) {
        #pragma unroll
        for (int c = 0; c < 2; ++c) {
            int cid = t + 256 * c;              // 0..511
            int row = cid >> 2, col = (cid & 3) * 8;
            s16x8 va = *(const s16x8*)(A + (size_t)(m0 + row) * K + k0 + col);
            *(s16x8*)(&As[row][col]) = va;
            s16x8 vb = *(const s16x8*)(BT + (size_t)(n0 + row) * K + k0 + col);
            *(s16x8*)(&Bs[row][col]) = vb;
        }
        __syncthreads();
        s16x8 af[4], bfr[4];
        #pragma unroll
        for (int i = 0; i < 4; ++i) af[i] = *(const s16x8*)(&As[wm + i * 16 + lr][lg * 8]);
        #pragma unroll
        for (int j = 0; j < 4; ++j) bfr[j] = *(const s16x8*)(&Bs[wn + j * 16 + lr][lg * 8]);
        #pragma unroll
        for (int i = 0; i < 4; ++i)
            #pragma unroll
            for (int j = 0; j < 4; ++j)
                acc[i][j] = MFMA16(af[i], bfr[j], acc[i][j]);
        __syncthreads();
    }

    if (OUT == 0) {
        ushort* out = (ushort*)outp;
        #pragma unroll
        for (int i = 0; i < 4; ++i)
            #pragma unroll
            for (int j = 0; j < 4; ++j) {
                int col = n0 + wn + j * 16 + lr;
                float bv = bias[col];
                #pragma unroll
                for (int r = 0; r < 4; ++r) {
                    int row = m0 + wm + i * 16 + lg * 4 + r;
                    out[(size_t)row * N + col] = f2bf(acc[i][j][r] + bv);
                }
            }
    } else if (OUT == 1) {
        ushort* Vt = (ushort*)outp;
        #pragma unroll
        for (int i = 0; i < 4; ++i)
            #pragma unroll
            for (int j = 0; j < 4; ++j) {
                int col = n0 + wn + j * 16 + lr;
                float bv = bias[col];
                int hh = col >> 8, v = col & 255;
                #pragma unroll
                for (int r = 0; r < 4; ++r) {
                    int row = m0 + wm + i * 16 + lg * 4 + r;
                    int bb = row / 300, key = row - bb * 300;
                    size_t addr = ((((size_t)bb * 8 + hh) * 10 + (key >> 5)) * 256 + v) * 32 + (key & 31);
                    Vt[addr] = f2bf(acc[i][j][r] + bv);
                }
            }
    } else {
        float* out = (float*)outp;
        #pragma unroll
        for (int i = 0; i < 4; ++i)
            #pragma unroll
            for (int j = 0; j < 4; ++j) {
                int col = n0 + wn + j * 16 + lr;
                float bv = bias[col];
                #pragma unroll
                for (int r = 0; r < 4; ++r) {
                    int row = m0 + wm + i * 16 + lg * 4 + r;
                    size_t idx = (size_t)row * N + col;
                    out[idx] = acc[i][j][r] + bv + resid[idx];
                }
            }
    }
}

// ---------------- fused attention per (q-tile, h, b) ----------------
// S^T = mfma(G, Q): lane holds one softmax row (q = lane&15) -> scalar softmax.
// PV: V chunks staged to LDS (coalesced, reg-double-buffered).
__global__ __launch_bounds__(256) void k_attn(const ushort* __restrict__ qf_bf,
                                              const ushort* __restrict__ G_bf,
                                              const ushort* __restrict__ Vt,
                                              const float* __restrict__ wb,
                                              const float* __restrict__ bias,
                                              ushort* __restrict__ O) {
    __shared__ ushort P[64][328];    // 64 q-rows x 320 keys (stride 328 -> 2-way max)
    __shared__ ushort Vs[256][40];   // one 32-key chunk of V, pad 32->40
    int qt = blockIdx.x, h = blockIdx.y, b = blockIdx.z;
    int t = threadIdx.x, l = t & 63, w = t >> 6;
    int lr = l & 15, lg = l >> 4;

    // prefetch V chunk 0 into registers (hides under scores phase)
    const ushort* vtbase = Vt + (size_t)((b * 8 + h) * 10) * 8192;
    s16x8 vr[4];
    #pragma unroll
    for (int i = 0; i < 4; ++i)
        vr[i] = *(const s16x8*)(vtbase + (size_t)(i * 256 + t) * 8);

    // Q fragment (B operand): col = q = lane&15
    int qr = min(qt * 64 + w * 16 + lr, 299);
    const ushort* qp = qf_bf + ((size_t)(b * 300 + qr)) * 512 + h * 64 + lg * 8;
    s16x8 q0 = *(const s16x8*)(qp);
    s16x8 q1 = *(const s16x8*)(qp + 32);

    // ---- scores^T + gelu in registers: sc[kt][r] at k = kt*16+lg*4+r, q = qr ----
    float sc[19][4];
    #pragma unroll
    for (int kt = 0; kt < 19; ++kt) {
        int key = kt * 16 + lr;
        int kcl = min(key, 299);
        const ushort* gp = G_bf + ((size_t)(b * 300 + kcl)) * 512 + h * 64 + lg * 8;
        s16x8 g0 = *(const s16x8*)(gp);
        s16x8 g1 = *(const s16x8*)(gp + 32);
        f32x4 a = (f32x4){0.f, 0.f, 0.f, 0.f};
        a = MFMA16(g0, q0, a);
        a = MFMA16(g1, q1, a);
        int k0 = kt * 16 + lg * 4;
        int k0c = min(k0, 296);
        size_t bidx = ((size_t)h * 300 + qr) * 300 + k0c;
        float4 wv = *(const float4*)(wb + bidx);
        float4 bv = *(const float4*)(bias + bidx);
        bool vmask = (kt < 18) || (lg < 3);
        #pragma unroll
        for (int r = 0; r < 4; ++r) {
            float x = a[r] * (&wv.x)[r] + (&bv.x)[r];
            sc[kt][r] = vmask ? gelu_exact(x) : -3.0e38f;
        }
    }

    // ---- per-lane softmax (row q=qr), reduce across lg groups ----
    float m = -3.0e38f;
    #pragma unroll
    for (int kt = 0; kt < 19; ++kt)
        #pragma unroll
        for (int r = 0; r < 4; ++r) m = fmaxf(m, sc[kt][r]);
    m = fmaxf(m, __shfl_xor(m, 16));
    m = fmaxf(m, __shfl_xor(m, 32));
    float s = 0.f;
    #pragma unroll
    for (int kt = 0; kt < 19; ++kt)
        #pragma unroll
        for (int r = 0; r < 4; ++r) {
            float p = __expf(sc[kt][r] - m);
            sc[kt][r] = p;
            s += p;
        }
    s += __shfl_xor(s, 16);
    s += __shfl_xor(s, 32);
    float inv = 1.0f / s;

    int qq = w * 16 + lr;
    #pragma unroll
    for (int kt = 0; kt < 19; ++kt) {
        s16x4 pw;
        #pragma unroll
        for (int r = 0; r < 4; ++r) pw[r] = (short)f2bf(sc[kt][r] * inv);
        *(s16x4*)(&P[qq][kt * 16 + lg * 4]) = pw;
    }
    // zero pad keys 304..319
    *(s16x4*)(&P[t >> 2][304 + (t & 3) * 4]) = (s16x4){0, 0, 0, 0};

    // ---- PV: O[16q x 256v] per wave, 10 LDS-staged chunks of 32 keys ----
    f32x4 acc[16];
    #pragma unroll
    for (int nt = 0; nt < 16; ++nt) acc[nt] = (f32x4){0.f, 0.f, 0.f, 0.f};

    #pragma unroll
    for (int kc = 0; kc < 10; ++kc) {
        #pragma unroll
        for (int i = 0; i < 4; ++i) {
            int e = i * 256 + t;
            *(s16x8*)(&Vs[e >> 2][(e & 3) * 8]) = vr[i];
        }
        s16x8 vn[4];
        if (kc < 9) {
            const ushort* nb = vtbase + (size_t)(kc + 1) * 8192;
            #pragma unroll
            for (int i = 0; i < 4; ++i)
                vn[i] = *(const s16x8*)(nb + (size_t)(i * 256 + t) * 8);
        }
        __syncthreads();     // Vs (and on kc=0, P) ready
        s16x8 pa = *(const s16x8*)(&P[w * 16 + lr][kc * 32 + lg * 8]);
        #pragma unroll
        for (int nt = 0; nt < 16; ++nt) {
            s16x8 vb = *(const s16x8*)(&Vs[nt * 16 + lr][lg * 8]);
            acc[nt] = MFMA16(pa, vb, acc[nt]);
        }
        __syncthreads();     // reads done before next overwrite
        if (kc < 9) {
            #pragma unroll
            for (int i = 0; i < 4; ++i) vr[i] = vn[i];
        }
    }

    // ---- store O: q = qt*64 + w*16 + lg*4 + r, v = nt*16 + lr ----
    #pragma unroll
    for (int nt = 0; nt < 16; ++nt)
        #pragma unroll
        for (int r = 0; r < 4; ++r) {
            int q = qt * 64 + w * 16 + lg * 4 + r;
            if (q < 300)
                O[((size_t)(b * 300 + q)) * 2048 + h * 256 + nt * 16 + lr] = f2bf(acc[nt][r]);
        }
}

extern "C" void kernel_launch(void* const* d_in, const int* in_sizes, int n_in,
                              void* d_out, int out_size, void* d_ws, size_t ws_size,
                              hipStream_t stream) {
    const float* qf    = (const float*)d_in[0];
    const float* bias  = (const float*)d_in[1];
    const float* W_gen = (const float*)d_in[2];
    const float* b_gen = (const float*)d_in[3];
    const float* W_val = (const float*)d_in[4];
    const float* b_val = (const float*)d_in[5];
    const float* W_out = (const float*)d_in[6];
    const float* b_out = (const float*)d_in[7];
    const float* wb    = (const float*)d_in[8];
    float* out = (float*)d_out;

    char* ws = (char*)d_ws;
    ushort* qf_bf = (ushort*)(ws);                       // 19,660,800 B
    ushort* G_bf  = (ushort*)(ws + 19660800);            // 19,660,800 B
    ushort* Vt    = (ushort*)(ws + 39321600);            // 83,886,080 B (tiled)
    ushort* O_bf  = (ushort*)(ws + 123207680);           // 78,643,200 B
    ushort* WgT   = (ushort*)(ws + 201850880);           //    524,288 B
    ushort* WvT   = (ushort*)(ws + 202375168);           //  2,097,152 B
    ushort* WoT   = (ushort*)(ws + 204472320);           //  2,097,152 B

    // stage 0: conversions / transposes / pad
    k_cvt<<<dim3(9600), dim3(256), 0, stream>>>(qf, qf_bf, 9830400);
    k_twT<<<dim3(16, 16), dim3(256), 0, stream>>>(W_gen, WgT, 512, 512);
    k_twT<<<dim3(16, 64), dim3(256), 0, stream>>>(W_val, WvT, 512, 2048);
    k_twT<<<dim3(64, 16), dim3(256), 0, stream>>>(W_out, WoT, 2048, 512);
    k_padVt<<<dim3(10240), dim3(256), 0, stream>>>(Vt);

    // stage 1: G = qf@W_gen + b_gen ; V (tiled) = (qf@W_val + b_val)
    k_gemm<0><<<dim3(150, 4),  dim3(256), 0, stream>>>(qf_bf, WgT, b_gen, nullptr, G_bf, 19200, 512, 512);
    k_gemm<1><<<dim3(150, 16), dim3(256), 0, stream>>>(qf_bf, WvT, b_val, nullptr, Vt,   19200, 2048, 512);

    // stage 2: fused attention
    k_attn<<<dim3(5, 8, 64), dim3(256), 0, stream>>>(qf_bf, G_bf, Vt, wb, bias, O_bf);

    // stage 3: out = O @ W_out + b_out + qf
    k_gemm<2><<<dim3(150, 4), dim3(256), 0, stream>>>(O_bf, WoT, b_out, qf, out, 19200, 512, 2048);
}

// Round 3
// 486.288 us; speedup vs baseline: 1.8415x; 1.0346x over previous
//
#include <hip/hip_runtime.h>
#include <hip/hip_bf16.h>

typedef __attribute__((ext_vector_type(4))) float f32x4;
typedef __attribute__((ext_vector_type(8))) short s16x8;
typedef __attribute__((ext_vector_type(4))) short s16x4;

#define MFMA16(A, B, C) __builtin_amdgcn_mfma_f32_16x16x32_bf16((A), (B), (C), 0, 0, 0)

#define GLDS16(gsrc, ldst) __builtin_amdgcn_global_load_lds(                   \
    (const __attribute__((address_space(1))) void*)(gsrc),                    \
    (__attribute__((address_space(3))) void*)(ldst), 16, 0, 0)

__device__ __forceinline__ ushort f2bf(float f) {
    __hip_bfloat16 h = __float2bfloat16(f);
    return *reinterpret_cast<ushort*>(&h);
}

// branchless exact GELU via Abramowitz-Stegun 7.1.26 erf (|err| <= 1.5e-7)
__device__ __forceinline__ float gelu_exact(float x) {
    float z = 0.70710678118f * x;
    float az = fabsf(z);
    float t = 1.0f / fmaf(0.3275911f, az, 1.0f);
    float poly = t * (0.254829592f + t * (-0.284496736f + t * (1.421413741f +
                 t * (-1.453152027f + t * 1.061405429f))));
    float e = __expf(-az * az);
    float erfv = copysignf(1.0f - poly * e, z);
    return 0.5f * x * (1.0f + erfv);
}

// ---------------- convert fp32 -> bf16 (vectorized x4) ----------------
__global__ void k_cvt(const float* __restrict__ in, ushort* __restrict__ out, int n) {
    int i = (blockIdx.x * 256 + threadIdx.x) * 4;
    if (i + 3 >= n) return;
    float4 v = *(const float4*)(in + i);
    ushort4 o;
    o.x = f2bf(v.x); o.y = f2bf(v.y); o.z = f2bf(v.z); o.w = f2bf(v.w);
    *(ushort4*)(out + i) = o;
}

// ---------------- transpose weight [K,N] f32 -> [N,K] bf16 ----------------
__global__ void k_twT(const float* __restrict__ w, ushort* __restrict__ wt, int K, int N) {
    __shared__ float tile[32][33];
    int k0 = blockIdx.x * 32, n0 = blockIdx.y * 32;
    int tx = threadIdx.x & 31, ty = threadIdx.x >> 5;   // 32 x 8
    #pragma unroll
    for (int i = ty; i < 32; i += 8)
        tile[i][tx] = w[(size_t)(k0 + i) * N + n0 + tx];
    __syncthreads();
    #pragma unroll
    for (int i = ty; i < 32; i += 8)
        wt[(size_t)(n0 + i) * K + k0 + tx] = f2bf(tile[tx][i]);
}

// ---------------- zero key-pad (keys 300..319) in tiled Vt ----------------
// Vt tiled layout: [(b*8+h)][kc(10)][v(256)][k32(32)] ushort
__global__ void k_padVt(ushort* __restrict__ Vt) {
    int i = blockIdx.x * 256 + threadIdx.x;   // < 131072*20
    int row = i / 20;                // (b*8+h)*256 + v
    int k = 300 + (i - row * 20);    // 300..319
    int bh = row >> 8, v = row & 255;
    Vt[(((size_t)bh * 10 + 9) * 256 + v) * 32 + (k - 288)] = 0;
}

// ---------------- GEMM: A[M,K]bf16 @ BT[N,K]bf16^T + bias ----------------
// m97 structure: global_load_lds width-16 staging, linear LDS [128][32].
// Grid: 1D, 152*GY blocks (GX=150 padded to 152=19*8 for XCD chunking).
// OUT=0: bf16 [M,N].  OUT=1: bf16 tiled Vt.  OUT=2: f32 [M,N] + bias + resid.
template <int OUT>
__global__ __launch_bounds__(256) void k_gemm(const ushort* __restrict__ A,
                                              const ushort* __restrict__ BT,
                                              const float* __restrict__ bias,
                                              const float* __restrict__ resid,
                                              void* __restrict__ outp,
                                              int N, int K, int GY) {
    __shared__ __align__(16) ushort As[128][32];
    __shared__ __align__(16) ushort Bs[128][32];
    int id = blockIdx.x;
    int xcd = id & 7, s = id >> 3;          // s in [0, 19*GY)
    int mxl = s / GY, ny = s - mxl * GY;
    int mx = xcd * 19 + mxl;
    if (mx >= 150) return;
    int m0 = mx * 128, n0 = ny * 128;

    int t = threadIdx.x, l = t & 63, w = t >> 6;
    int wm = (w >> 1) * 64, wn = (w & 1) * 64;
    int lr = l & 15, lg = l >> 4;
    ushort* AsF = &As[0][0];
    ushort* BsF = &Bs[0][0];

    f32x4 acc[4][4];
    #pragma unroll
    for (int i = 0; i < 4; ++i)
        #pragma unroll
        for (int j = 0; j < 4; ++j)
            acc[i][j] = (f32x4){0.f, 0.f, 0.f, 0.f};

    for (int k0 = 0; k0 < K; k0 += 32) {
        // stage 8KB A-tile + 8KB B-tile: 512 x 16B chunks each, 2 calls/wave each
        #pragma unroll
        for (int c = 0; c < 2; ++c) {
            int cb = w * 128 + c * 64;          // wave-uniform chunk base
            int ch = cb + l;
            int row = ch >> 2, col = (ch & 3) * 8;
            GLDS16(A + (size_t)(m0 + row) * K + k0 + col, AsF + (size_t)cb * 8);
            GLDS16(BT + (size_t)(n0 + row) * K + k0 + col, BsF + (size_t)cb * 8);
        }
        __syncthreads();
        s16x8 af[4], bfr[4];
        #pragma unroll
        for (int i = 0; i < 4; ++i) af[i] = *(const s16x8*)(&As[wm + i * 16 + lr][lg * 8]);
        #pragma unroll
        for (int j = 0; j < 4; ++j) bfr[j] = *(const s16x8*)(&Bs[wn + j * 16 + lr][lg * 8]);
        #pragma unroll
        for (int i = 0; i < 4; ++i)
            #pragma unroll
            for (int j = 0; j < 4; ++j)
                acc[i][j] = MFMA16(af[i], bfr[j], acc[i][j]);
        __syncthreads();
    }

    if (OUT == 0) {
        ushort* out = (ushort*)outp;
        #pragma unroll
        for (int i = 0; i < 4; ++i)
            #pragma unroll
            for (int j = 0; j < 4; ++j) {
                int col = n0 + wn + j * 16 + lr;
                float bv = bias[col];
                #pragma unroll
                for (int r = 0; r < 4; ++r) {
                    int row = m0 + wm + i * 16 + lg * 4 + r;
                    out[(size_t)row * N + col] = f2bf(acc[i][j][r] + bv);
                }
            }
    } else if (OUT == 1) {
        ushort* Vt = (ushort*)outp;
        #pragma unroll
        for (int i = 0; i < 4; ++i)
            #pragma unroll
            for (int j = 0; j < 4; ++j) {
                int col = n0 + wn + j * 16 + lr;
                float bv = bias[col];
                int hh = col >> 8, v = col & 255;
                #pragma unroll
                for (int r = 0; r < 4; ++r) {
                    int row = m0 + wm + i * 16 + lg * 4 + r;
                    int bb = row / 300, key = row - bb * 300;
                    size_t addr = ((((size_t)bb * 8 + hh) * 10 + (key >> 5)) * 256 + v) * 32 + (key & 31);
                    Vt[addr] = f2bf(acc[i][j][r] + bv);
                }
            }
    } else {
        float* out = (float*)outp;
        #pragma unroll
        for (int i = 0; i < 4; ++i)
            #pragma unroll
            for (int j = 0; j < 4; ++j) {
                int col = n0 + wn + j * 16 + lr;
                float bv = bias[col];
                #pragma unroll
                for (int r = 0; r < 4; ++r) {
                    int row = m0 + wm + i * 16 + lg * 4 + r;
                    size_t idx = (size_t)row * N + col;
                    out[idx] = acc[i][j][r] + bv + resid[idx];
                }
            }
    }
}

// ---------------- fused attention ----------------
// Block remap for L2 locality: xcd = id&7 (HW round-robin), within-XCD order
// (h, bi, qt-inner); b = xcd*8 + bi. Vt slice reused by 5 consecutive qt
// blocks; wb/bias reused across 8 bi.
__global__ __launch_bounds__(256) void k_attn(const ushort* __restrict__ qf_bf,
                                              const ushort* __restrict__ G_bf,
                                              const ushort* __restrict__ Vt,
                                              const float* __restrict__ wb,
                                              const float* __restrict__ bias,
                                              ushort* __restrict__ O) {
    __shared__ __align__(16) ushort P[64][320];      // 40,960 B (per-wave private rows)
    __shared__ __align__(16) ushort Vs[2][256][40];  // 40,960 B double-buffered
    int id = blockIdx.x;
    int xcd = id & 7, s = id >> 3;        // s in [0,320)
    int h = s / 40; int r2 = s - h * 40;
    int bi = r2 / 5, qt = r2 - bi * 5;
    int b = xcd * 8 + bi;

    int t = threadIdx.x, l = t & 63, w = t >> 6;
    int lr = l & 15, lg = l >> 4;

    // Q fragment (B operand): col = q = lane&15
    int qr = min(qt * 64 + w * 16 + lr, 299);
    const ushort* qp = qf_bf + ((size_t)(b * 300 + qr)) * 512 + h * 64 + lg * 8;
    s16x8 q0 = *(const s16x8*)(qp);
    s16x8 q1 = *(const s16x8*)(qp + 32);

    // ---- scores^T + gelu in registers: sc[kt][r] at k = kt*16+lg*4+r, q = qr ----
    float sc[19][4];
    #pragma unroll
    for (int kt = 0; kt < 19; ++kt) {
        int key = kt * 16 + lr;
        int kcl = min(key, 299);
        const ushort* gp = G_bf + ((size_t)(b * 300 + kcl)) * 512 + h * 64 + lg * 8;
        s16x8 g0 = *(const s16x8*)(gp);
        s16x8 g1 = *(const s16x8*)(gp + 32);
        f32x4 a = (f32x4){0.f, 0.f, 0.f, 0.f};
        a = MFMA16(g0, q0, a);
        a = MFMA16(g1, q1, a);
        int k0 = kt * 16 + lg * 4;
        int k0c = min(k0, 296);
        size_t bidx = ((size_t)h * 300 + qr) * 300 + k0c;
        float4 wv = *(const float4*)(wb + bidx);
        float4 bv = *(const float4*)(bias + bidx);
        bool vmask = (kt < 18) || (lg < 3);
        #pragma unroll
        for (int r = 0; r < 4; ++r) {
            float x = a[r] * (&wv.x)[r] + (&bv.x)[r];
            sc[kt][r] = vmask ? gelu_exact(x) : -3.0e38f;
        }
    }

    // prefetch V chunk 0 (L2-hot after swizzle); lands during softmax VALU
    const ushort* vtbase = Vt + (size_t)((b * 8 + h) * 10) * 8192;
    s16x8 vr[4];
    #pragma unroll
    for (int i = 0; i < 4; ++i)
        vr[i] = *(const s16x8*)(vtbase + (size_t)(i * 256 + t) * 8);

    // ---- per-lane softmax (row q=qr), reduce across lg groups ----
    float m = -3.0e38f;
    #pragma unroll
    for (int kt = 0; kt < 19; ++kt)
        #pragma unroll
        for (int r = 0; r < 4; ++r) m = fmaxf(m, sc[kt][r]);
    m = fmaxf(m, __shfl_xor(m, 16));
    m = fmaxf(m, __shfl_xor(m, 32));
    float ssum = 0.f;
    #pragma unroll
    for (int kt = 0; kt < 19; ++kt)
        #pragma unroll
        for (int r = 0; r < 4; ++r) {
            float p = __expf(sc[kt][r] - m);
            sc[kt][r] = p;
            ssum += p;
        }
    ssum += __shfl_xor(ssum, 16);
    ssum += __shfl_xor(ssum, 32);
    float inv = 1.0f / ssum;

    int qq = w * 16 + lr;
    #pragma unroll
    for (int kt = 0; kt < 19; ++kt) {
        s16x4 pw;
        #pragma unroll
        for (int r = 0; r < 4; ++r) pw[r] = (short)f2bf(sc[kt][r] * inv);
        *(s16x4*)(&P[qq][kt * 16 + lg * 4]) = pw;
    }
    // zero pad keys 304..319
    *(s16x4*)(&P[t >> 2][304 + (t & 3) * 4]) = (s16x4){0, 0, 0, 0};

    // write chunk 0 to Vs[0]; issue chunk 1 loads (consumed after next sync)
    #pragma unroll
    for (int i = 0; i < 4; ++i) {
        int e = i * 256 + t;
        *(s16x8*)(&Vs[0][e >> 2][(e & 3) * 8]) = vr[i];
    }
    #pragma unroll
    for (int i = 0; i < 4; ++i)
        vr[i] = *(const s16x8*)(vtbase + 8192 + (size_t)(i * 256 + t) * 8);

    // ---- PV: O[16q x 256v] per wave, dbuf LDS chunks, 1 sync per chunk ----
    f32x4 acc[16];
    #pragma unroll
    for (int nt = 0; nt < 16; ++nt) acc[nt] = (f32x4){0.f, 0.f, 0.f, 0.f};

    #pragma unroll
    for (int kc = 0; kc < 10; ++kc) {
        __syncthreads();                 // Vs[kc&1] writes visible to all waves
        int cur = kc & 1;
        s16x8 pa = *(const s16x8*)(&P[w * 16 + lr][kc * 32 + lg * 8]);
        __builtin_amdgcn_s_setprio(1);
        #pragma unroll
        for (int nt = 0; nt < 16; ++nt) {
            s16x8 vb = *(const s16x8*)(&Vs[cur][nt * 16 + lr][lg * 8]);
            acc[nt] = MFMA16(pa, vb, acc[nt]);
        }
        __builtin_amdgcn_s_setprio(0);
        if (kc < 9) {
            // write chunk kc+1 (readers of this buffer finished before top sync)
            #pragma unroll
            for (int i = 0; i < 4; ++i) {
                int e = i * 256 + t;
                *(s16x8*)(&Vs[cur ^ 1][e >> 2][(e & 3) * 8]) = vr[i];
            }
            if (kc < 8) {
                const ushort* nb = vtbase + (size_t)(kc + 2) * 8192;
                #pragma unroll
                for (int i = 0; i < 4; ++i)
                    vr[i] = *(const s16x8*)(nb + (size_t)(i * 256 + t) * 8);
            }
        }
    }

    // ---- store O: q = qt*64 + w*16 + lg*4 + r, v = nt*16 + lr ----
    #pragma unroll
    for (int nt = 0; nt < 16; ++nt)
        #pragma unroll
        for (int r = 0; r < 4; ++r) {
            int q = qt * 64 + w * 16 + lg * 4 + r;
            if (q < 300)
                O[((size_t)(b * 300 + q)) * 2048 + h * 256 + nt * 16 + lr] = f2bf(acc[nt][r]);
        }
}

extern "C" void kernel_launch(void* const* d_in, const int* in_sizes, int n_in,
                              void* d_out, int out_size, void* d_ws, size_t ws_size,
                              hipStream_t stream) {
    const float* qf    = (const float*)d_in[0];
    const float* bias  = (const float*)d_in[1];
    const float* W_gen = (const float*)d_in[2];
    const float* b_gen = (const float*)d_in[3];
    const float* W_val = (const float*)d_in[4];
    const float* b_val = (const float*)d_in[5];
    const float* W_out = (const float*)d_in[6];
    const float* b_out = (const float*)d_in[7];
    const float* wb    = (const float*)d_in[8];
    float* out = (float*)d_out;

    char* ws = (char*)d_ws;
    ushort* qf_bf = (ushort*)(ws);                       // 19,660,800 B
    ushort* G_bf  = (ushort*)(ws + 19660800);            // 19,660,800 B
    ushort* Vt    = (ushort*)(ws + 39321600);            // 83,886,080 B (tiled)
    ushort* O_bf  = (ushort*)(ws + 123207680);           // 78,643,200 B
    ushort* WgT   = (ushort*)(ws + 201850880);           //    524,288 B
    ushort* WvT   = (ushort*)(ws + 202375168);           //  2,097,152 B
    ushort* WoT   = (ushort*)(ws + 204472320);           //  2,097,152 B

    // stage 0: conversions / transposes / pad
    k_cvt<<<dim3(9600), dim3(256), 0, stream>>>(qf, qf_bf, 9830400);
    k_twT<<<dim3(16, 16), dim3(256), 0, stream>>>(W_gen, WgT, 512, 512);
    k_twT<<<dim3(16, 64), dim3(256), 0, stream>>>(W_val, WvT, 512, 2048);
    k_twT<<<dim3(64, 16), dim3(256), 0, stream>>>(W_out, WoT, 2048, 512);
    k_padVt<<<dim3(10240), dim3(256), 0, stream>>>(Vt);

    // stage 1: G = qf@W_gen + b_gen ; V (tiled) = (qf@W_val + b_val)
    k_gemm<0><<<dim3(152 * 4),  dim3(256), 0, stream>>>(qf_bf, WgT, b_gen, nullptr, G_bf, 512, 512, 4);
    k_gemm<1><<<dim3(152 * 16), dim3(256), 0, stream>>>(qf_bf, WvT, b_val, nullptr, Vt, 2048, 512, 16);

    // stage 2: fused attention
    k_attn<<<dim3(2560), dim3(256), 0, stream>>>(qf_bf, G_bf, Vt, wb, bias, O_bf);

    // stage 3: out = O @ W_out + b_out + qf
    k_gemm<2><<<dim3(152 * 4), dim3(256), 0, stream>>>(O_bf, WoT, b_out, qf, out, 512, 2048, 4);
}